// Round 1
// 1632.819 us; speedup vs baseline: 1.3722x; 1.3722x over previous
//
#include <hip/hip_runtime.h>
#include <math.h>

// Problem constants (fixed by reference)
constexpr int T  = 128;
constexpr int B  = 512;
constexpr int Hd = 256;
constexpr int M  = 64;
constexpr int SP = 264;   // A-plane row stride in u16 (rows land 4 banks apart)

// ---- MFMA frag types (gfx950 mfma_f32_16x16x32_f16: A/B = 8 f16, C/D = 4 f32) ----
typedef __attribute__((ext_vector_type(8))) _Float16       half8;
typedef __attribute__((ext_vector_type(4))) _Float16       half4;
typedef __attribute__((ext_vector_type(4))) float          f32x4;
typedef __attribute__((ext_vector_type(4))) unsigned int   u32x4;
typedef __attribute__((ext_vector_type(4))) unsigned short u16x4;

union FragA { u32x4 u; half8 h; };

// f16 2-term split: v ~= hi + lo (22 mantissa bits total ~ f32).
__device__ __forceinline__ void splith(float v, unsigned short& h, unsigned short& l) {
    _Float16 hf = (_Float16)v;
    _Float16 lf = (_Float16)(v - (float)hf);
    h = __builtin_bit_cast(unsigned short, hf);
    l = __builtin_bit_cast(unsigned short, lf);
}

// ---------------- prep kernels (unchanged) ----------------

// KC[m][h] = keys[m] @ V[:,h]  (f32, tiny)
__global__ __launch_bounds__(256) void k_kc(const float* __restrict__ keys,
                                            const float* __restrict__ V,
                                            float* __restrict__ KCo) {
    const int m = blockIdx.x, h = threadIdx.x;
    float a = 0.f;
#pragma unroll 4
    for (int k = 0; k < 256; ++k) a = fmaf(keys[m * 256 + k], V[k * 256 + h], a);
    KCo[m * 256 + h] = a;
}

// U -> f16 fragments. UBf[kt(8)][ht(16)][lane(64)][j(8)]: k=kt*32+(l>>4)*8+j, h=ht*16+(l&15)
// NOTE: identical lane layout serves as EITHER the B-frag of state@U (value U[k][h], col=h)
// OR the A-frag of U^T@state^T (value U^T[h][k], row=h). We now use it as A.
__global__ __launch_bounds__(256) void k_fragU(const float* __restrict__ U,
                                               _Float16* __restrict__ UBf) {
    const int idx = blockIdx.x * 256 + threadIdx.x;   // [0, 65536)
    const int j = idx & 7, l = (idx >> 3) & 63, ht = (idx >> 9) & 15, kt = idx >> 13;
    const int q = l >> 4, n = l & 15;
    UBf[idx] = (_Float16)U[(kt * 32 + q * 8 + j) * 256 + ht * 16 + n];
}

// [W | keys^T] -> f16 B-fragments for the SW/KS prep GEMM.
__global__ __launch_bounds__(256) void k_fragW(const float* __restrict__ W,
                                               const float* __restrict__ keys,
                                               _Float16* __restrict__ WBf) {
    const int idx = blockIdx.x * 256 + threadIdx.x;   // [0, 81920)
    const int j = idx & 7, l = (idx >> 3) & 63;
    const int ht = (idx >> 9) % 20, kt = idx / (512 * 20);
    const int q = l >> 4, n = l & 15;
    const int k = kt * 32 + q * 8 + j;
    float v = (ht < 16) ? W[k * 256 + ht * 16 + n]
                        : keys[((ht - 16) * 16 + n) * 256 + k];
    WBf[idx] = (_Float16)v;
}

// SW[tb][h] (f16) = stories[tb]@W  and  KS[tb][m] (f32) = stories[tb].keys[m]
__global__ __launch_bounds__(256, 4) void k_swks(const float* __restrict__ S,
                                                 const _Float16* __restrict__ WBf,
                                                 _Float16* __restrict__ SWo,
                                                 float* __restrict__ KSo) {
    const int tid = threadIdx.x, w = tid >> 6, l = tid & 63;
    const int col = l & 15, q = l >> 4;
    const size_t tb0 = ((size_t)blockIdx.x * 4 + w) * 16;

    f32x4 acc[20];
#pragma unroll
    for (int ht = 0; ht < 20; ++ht) acc[ht] = (f32x4)(0.f);

#pragma unroll
    for (int kt = 0; kt < 8; ++kt) {
        const float* ar = S + (tb0 + col) * 256 + kt * 32 + q * 8;
        f32x4 a0 = *(const f32x4*)ar;
        f32x4 a1 = *(const f32x4*)(ar + 4);
        FragA ah, al;
#pragma unroll
        for (int j = 0; j < 4; ++j) {
            _Float16 h0 = (_Float16)a0[j];
            ah.h[j] = h0; al.h[j] = (_Float16)(a0[j] - (float)h0);
            _Float16 h1 = (_Float16)a1[j];
            ah.h[4 + j] = h1; al.h[4 + j] = (_Float16)(a1[j] - (float)h1);
        }
        const _Float16* bp = WBf + ((size_t)kt * 20 * 64 + l) * 8;
#pragma unroll
        for (int ht = 0; ht < 20; ++ht) {
            FragA fb; fb.u = *(const u32x4*)(bp + ht * 512);
            acc[ht] = __builtin_amdgcn_mfma_f32_16x16x32_f16(ah.h, fb.h, acc[ht], 0, 0, 0);
            acc[ht] = __builtin_amdgcn_mfma_f32_16x16x32_f16(al.h, fb.h, acc[ht], 0, 0, 0);
        }
    }
#pragma unroll
    for (int ht = 0; ht < 20; ++ht)
#pragma unroll
        for (int r = 0; r < 4; ++r) {
            size_t tbr = tb0 + q * 4 + r;
            if (ht < 16) SWo[tbr * 256 + ht * 16 + col] = (_Float16)acc[ht][r];
            else         KSo[tbr * 64 + (ht - 16) * 16 + col] = acc[ht][r];
        }
}

// gates transpose: GT[bg=b*4+mt][t*16+row] -> out[t][mt*16+row][b]
__global__ __launch_bounds__(256) void k_gt(const float* __restrict__ GT,
                                            float* __restrict__ out) {
    __shared__ float tile[64][65];
    const int mt = blockIdx.x & 3;
    const int bT = (blockIdx.x >> 2) & 7;
    const int trT = blockIdx.x >> 5;
    const int tx = threadIdx.x & 63, ty = threadIdx.x >> 6;
    const int b0 = bT * 64, tr0 = trT * 64;
#pragma unroll 4
    for (int i = 0; i < 16; ++i) {
        int r = i * 4 + ty;
        tile[r][tx] = GT[((size_t)(b0 + r) * 4 + mt) * 2048 + tr0 + tx];
    }
    __syncthreads();
    const size_t gbase = (size_t)M * B * Hd;
#pragma unroll 4
    for (int i = 0; i < 16; ++i) {
        int r = i * 4 + ty;
        int tr = tr0 + r;
        out[gbase + (size_t)(tr >> 4) * (M * B) + (size_t)(mt * 16 + (tr & 15)) * B + b0 + tx]
            = tile[tx][r];
    }
}

// ---------------- main recurrent kernel ----------------
// TRANSPOSED GEMM: acc = U^T @ state^T  (swap MFMA operands; UBf is now the A operand,
// the LDS state-plane read is the B operand — both byte-identical to the old layout).
// C layout: lane holds ONE m (= l&15 = col) and 16 h values (4 hti x 4 consecutive r,
// h = (htb+hti)*16 + q*4 + r). This makes:
//   - gd/oc/cc reduction: 16 in-lane fmas + 2 shfl_xor per quantity (was 48 bpermutes)
//   - phase B: zero broadcast shuffles (g/Gm/scl born in the right lane, m == col)
//   - A-plane refresh: 8 ds_write_b64 of 4 consecutive u16 (was 32 scattered ds_write_u16)
__global__ __launch_bounds__(256, 2)
void dynmem_main(const float* __restrict__ stories, const float* __restrict__ mask,
                 const float* __restrict__ keys, const float* __restrict__ prelu_a,
                 const _Float16* __restrict__ SW, const float* __restrict__ KS,
                 const float* __restrict__ KC, const _Float16* __restrict__ UBf,
                 float* __restrict__ GT, float* __restrict__ out) {
    __shared__ __align__(16) unsigned short Aph[16 * SP];
    __shared__ __align__(16) unsigned short Apl[16 * SP];
    __shared__ __align__(16) float part[4][16][4];   // [wave][m-row][gd,oc,cc,pad]

    const int tid = threadIdx.x;
    const int w = tid >> 6, l = tid & 63;
    const int col = l & 15, q = l >> 4;     // col = this lane's m-row; q = h sub-block
    const int hq  = q * 4;                  // h offset within a 16-tile
    const int htb = w * 4;                  // this wave's 4 h-out tiles
    const int b  = blockIdx.x >> 2;
    const int mt = blockIdx.x & 3;
    const int m0 = mt * 16;
    const int bg = blockIdx.x;

    // ---- t-invariant: U^T A-fragments resident in VGPRs (same data as old B-frags) ----
    FragA bfr[8][4];
#pragma unroll
    for (int kt = 0; kt < 8; ++kt)
#pragma unroll
        for (int hti = 0; hti < 4; ++hti)
            bfr[kt][hti].u = *(const u32x4*)(UBf + ((size_t)(kt * 16 + htb + hti) * 64 + l) * 8);

    f32x4 pa_l[4], old_[4], kc_l[4];
#pragma unroll
    for (int hti = 0; hti < 4; ++hti) {
        const int h0 = (htb + hti) * 16 + hq;
        pa_l[hti] = *(const f32x4*)(prelu_a + h0);
        old_[hti] = *(const f32x4*)(keys + (m0 + col) * Hd + h0);
        kc_l[hti] = *(const f32x4*)(KC + (m0 + col) * Hd + h0);
    }
    // okk = ||keys[m0+col]||^2 (for t=0 norm; afterwards ||old||==1)
    float okk = 0.f;
    {
        const float* kr = keys + (m0 + col) * Hd;
#pragma unroll 4
        for (int k = 0; k < 256; k += 4) {
            f32x4 kv = *(const f32x4*)(kr + k);
            okk = fmaf(kv[0], kv[0], okk); okk = fmaf(kv[1], kv[1], okk);
            okk = fmaf(kv[2], kv[2], okk); okk = fmaf(kv[3], kv[3], okk);
        }
    }
    // init A-planes = keys (unnormalized per reference); row = m = col, 4 consecutive u16
#pragma unroll
    for (int hti = 0; hti < 4; ++hti) {
        u16x4 vh, vl;
#pragma unroll
        for (int r = 0; r < 4; ++r) {
            unsigned short hh, ll;
            splith(old_[hti][r], hh, ll);
            vh[r] = hh; vl[r] = ll;
        }
        *(u16x4*)(Aph + col * SP + (htb + hti) * 16 + hq) = vh;
        *(u16x4*)(Apl + col * SP + (htb + hti) * 16 + hq) = vl;
    }
    __syncthreads();

    for (int t = 0; t < T; ++t) {
        const size_t tb = (size_t)t * B + b;
        const float mv = mask[t * B + b];
        const float ksR = KS[tb * 64 + m0 + col];     // this lane's m = col
        f32x4 sent_v[4]; half4 sw_v[4];
#pragma unroll
        for (int hti = 0; hti < 4; ++hti) {
            const int h0 = (htb + hti) * 16 + hq;
            sent_v[hti] = *(const f32x4*)(stories + tb * Hd + h0);
            sw_v[hti]   = *(const half4*)(SW + tb * Hd + h0);
        }

        // ---- MFMA: acc[hti] = (U^T @ state^T) tile; A = bfr (regs), B = LDS planes ----
        f32x4 acc[4];
#pragma unroll
        for (int hti = 0; hti < 4; ++hti) acc[hti] = (f32x4)(0.f);

#pragma unroll
        for (int kt = 0; kt < 8; ++kt) {
            const half8 sh = *(const half8*)(const void*)(Aph + col * SP + kt * 32 + q * 8);
            const half8 sl = *(const half8*)(const void*)(Apl + col * SP + kt * 32 + q * 8);
#pragma unroll
            for (int hti = 0; hti < 4; ++hti)
                acc[hti] = __builtin_amdgcn_mfma_f32_16x16x32_f16(bfr[kt][hti].h, sh, acc[hti], 0, 0, 0);
#pragma unroll
            for (int hti = 0; hti < 4; ++hti)
                acc[hti] = __builtin_amdgcn_mfma_f32_16x16x32_f16(bfr[kt][hti].h, sl, acc[hti], 0, 0, 0);
        }

        // ---- candidate + per-lane partials over this lane's 16 h values ----
        float gd = 0.f, oc = 0.f, cc = 0.f;
#pragma unroll
        for (int hti = 0; hti < 4; ++hti)
#pragma unroll
            for (int r = 0; r < 4; ++r) {
                float o = old_[hti][r];
                float x = acc[hti][r] + (float)sw_v[hti][r] + kc_l[hti][r];
                float c = (x < 0.f) ? pa_l[hti][r] * x : x;    // PReLU
                acc[hti][r] = c;                               // keep candidate
                gd = fmaf(o, sent_v[hti][r], gd);
                oc = fmaf(o, c, oc);
                cc = fmaf(c, c, cc);
            }
        // reduce across the 4 q-lanes sharing this m (= col): xor 16, 32
        gd += __shfl_xor(gd, 16); gd += __shfl_xor(gd, 32);
        oc += __shfl_xor(oc, 16); oc += __shfl_xor(oc, 32);
        cc += __shfl_xor(cc, 16); cc += __shfl_xor(cc, 32);
        if (q == 0) {
            f32x4 pv = {gd, oc, cc, 0.f};
            *(f32x4*)part[w][col] = pv;
        }
        __syncthreads();   // barrier 1: partials ready; all A-plane reads complete

        // ---- phase B: every lane finalizes its own m (= col); no broadcasts needed ----
        f32x4 p0 = *(const f32x4*)part[0][col];
        f32x4 p1 = *(const f32x4*)part[1][col];
        f32x4 p2 = *(const f32x4*)part[2][col];
        f32x4 p3 = *(const f32x4*)part[3][col];
        float gdS = p0[0] + p1[0] + p2[0] + p3[0];
        float ocS = p0[1] + p1[1] + p2[1] + p3[1];
        float ccS = p0[2] + p1[2] + p2[2] + p3[2];
        float g   = 1.f / (1.f + __expf(-(gdS + ksR)));
        float Gm  = g * mv;
        float ooc = (t == 0) ? okk : 1.0f;
        float nsq = fmaf(Gm, fmaf(Gm, ccS, 2.f * ocS), ooc);
        float scl = 1.f / fmaxf(sqrtf(nsq), 1e-12f);
        if (tid < 16) GT[(size_t)bg * 2048 + t * 16 + col] = g;

        // ---- state update + A-plane refresh (4 consecutive u16 per hti per plane) ----
#pragma unroll
        for (int hti = 0; hti < 4; ++hti) {
            u16x4 vh, vl;
#pragma unroll
            for (int r = 0; r < 4; ++r) {
                float n = fmaf(Gm, acc[hti][r], old_[hti][r]) * scl;
                old_[hti][r] = n;
                unsigned short hh, ll;
                splith(n, hh, ll);
                vh[r] = hh; vl[r] = ll;
            }
            *(u16x4*)(Aph + col * SP + (htb + hti) * 16 + hq) = vh;
            *(u16x4*)(Apl + col * SP + (htb + hti) * 16 + hq) = vl;
        }
        __syncthreads();   // barrier 2: A-planes ready for next step
    }

    // ---- final memory out [M,B,H], exact f32 from registers ----
#pragma unroll
    for (int hti = 0; hti < 4; ++hti)
        *(f32x4*)(out + ((size_t)(m0 + col) * B + b) * Hd + (htb + hti) * 16 + hq) = old_[hti];
}

extern "C" void kernel_launch(void* const* d_in, const int* in_sizes, int n_in,
                              void* d_out, int out_size, void* d_ws, size_t ws_size,
                              hipStream_t stream) {
    const float* stories = (const float*)d_in[0];
    const float* mask    = (const float*)d_in[1];
    const float* keys    = (const float*)d_in[2];
    const float* U       = (const float*)d_in[3];
    const float* W       = (const float*)d_in[4];
    const float* V       = (const float*)d_in[5];
    const float* prelu_a = (const float*)d_in[6];
    float* out = (float*)d_out;

    // workspace carve-up (~67.5 MB)
    _Float16* SW  = (_Float16*)d_ws;                   // 16,777,216 f16 (33.55 MB)
    float*    KS  = (float*)(SW + 16777216);           //  4,194,304 f32 (16.78 MB)
    float*    KC  = KS + 4194304;                      //     16,384 f32
    _Float16* UBf = (_Float16*)(KC + 16384);           //     65,536 f16
    _Float16* WBf = UBf + 65536;                       //     81,920 f16
    float*    GT  = (float*)(WBf + 81920);             //  4,194,304 f32 (16.78 MB)

    k_kc   <<<dim3(64),   dim3(256), 0, stream>>>(keys, V, KC);
    k_fragU<<<dim3(256),  dim3(256), 0, stream>>>(U, UBf);
    k_fragW<<<dim3(320),  dim3(256), 0, stream>>>(W, keys, WBf);
    k_swks <<<dim3(1024), dim3(256), 0, stream>>>(stories, WBf, SW, KS);
    dynmem_main<<<dim3(2048), dim3(256), 0, stream>>>(stories, mask, keys, prelu_a,
                                                      SW, KS, KC, UBf, GT, out);
    k_gt   <<<dim3(1024), dim3(256), 0, stream>>>(GT, out);
}

// Round 3
// 1454.448 us; speedup vs baseline: 1.5405x; 1.1226x over previous
//
#include <hip/hip_runtime.h>
#include <math.h>

// Problem constants (fixed by reference)
constexpr int T  = 128;
constexpr int B  = 512;
constexpr int Hd = 256;
constexpr int M  = 64;
constexpr int SP = 264;   // A-plane row stride in u16 (rows land 4 banks apart)
constexpr int KP = 260;   // kc LDS row stride in f32 (same 4-bank skew)

// ---- MFMA frag types (gfx950 mfma_f32_16x16x32_f16: A/B = 8 f16, C/D = 4 f32) ----
typedef __attribute__((ext_vector_type(8))) _Float16       half8;
typedef __attribute__((ext_vector_type(4))) _Float16       half4;
typedef __attribute__((ext_vector_type(2))) __fp16         fp16x2;   // cvt_pkrtz result type
typedef __attribute__((ext_vector_type(4))) float          f32x4;
typedef __attribute__((ext_vector_type(4))) unsigned int   u32x4;
typedef __attribute__((ext_vector_type(2))) unsigned int   u32x2;
typedef __attribute__((ext_vector_type(4))) unsigned short u16x4;

union FragA { u32x4 u; half8 h; };

// f16 2-term split of 4 values via packed converts. hi uses RTZ (pkrtz) — fine,
// since lo = v - (f32)hi compensates hi's rounding exactly; only lo's own f16
// rounding remains (~2^-22 relative), same class as before.
__device__ __forceinline__ void split4(const f32x4 v, u32x2& hh, u32x2& ll) {
    fp16x2 h01 = __builtin_amdgcn_cvt_pkrtz(v[0], v[1]);
    fp16x2 h23 = __builtin_amdgcn_cvt_pkrtz(v[2], v[3]);
    fp16x2 l01 = __builtin_amdgcn_cvt_pkrtz(v[0] - (float)h01[0], v[1] - (float)h01[1]);
    fp16x2 l23 = __builtin_amdgcn_cvt_pkrtz(v[2] - (float)h23[0], v[3] - (float)h23[1]);
    hh[0] = __builtin_bit_cast(unsigned int, h01);
    hh[1] = __builtin_bit_cast(unsigned int, h23);
    ll[0] = __builtin_bit_cast(unsigned int, l01);
    ll[1] = __builtin_bit_cast(unsigned int, l23);
}

// scalar split (init path only)
__device__ __forceinline__ void splith(float v, unsigned short& h, unsigned short& l) {
    _Float16 hf = (_Float16)v;
    _Float16 lf = (_Float16)(v - (float)hf);
    h = __builtin_bit_cast(unsigned short, hf);
    l = __builtin_bit_cast(unsigned short, lf);
}

// LDS-only barrier: drain LDS ops, sync waves, but leave global loads/stores
// (register prefetch, GT store) in flight. Memory clobbers fence compiler motion.
__device__ __forceinline__ void bar_lds() {
    asm volatile("s_waitcnt lgkmcnt(0)" ::: "memory");
    __builtin_amdgcn_s_barrier();
    asm volatile("" ::: "memory");
}

// ---------------- prep kernels (unchanged) ----------------

// KC[m][h] = keys[m] @ V[:,h]  (f32, tiny)
__global__ __launch_bounds__(256) void k_kc(const float* __restrict__ keys,
                                            const float* __restrict__ V,
                                            float* __restrict__ KCo) {
    const int m = blockIdx.x, h = threadIdx.x;
    float a = 0.f;
#pragma unroll 4
    for (int k = 0; k < 256; ++k) a = fmaf(keys[m * 256 + k], V[k * 256 + h], a);
    KCo[m * 256 + h] = a;
}

// U -> f16 fragments. UBf[kt(8)][ht(16)][lane(64)][j(8)]: k=kt*32+(l>>4)*8+j, h=ht*16+(l&15)
__global__ __launch_bounds__(256) void k_fragU(const float* __restrict__ U,
                                               _Float16* __restrict__ UBf) {
    const int idx = blockIdx.x * 256 + threadIdx.x;   // [0, 65536)
    const int j = idx & 7, l = (idx >> 3) & 63, ht = (idx >> 9) & 15, kt = idx >> 13;
    const int q = l >> 4, n = l & 15;
    UBf[idx] = (_Float16)U[(kt * 32 + q * 8 + j) * 256 + ht * 16 + n];
}

// [W | keys^T] -> f16 B-fragments for the SW/KS prep GEMM.
__global__ __launch_bounds__(256) void k_fragW(const float* __restrict__ W,
                                               const float* __restrict__ keys,
                                               _Float16* __restrict__ WBf) {
    const int idx = blockIdx.x * 256 + threadIdx.x;   // [0, 81920)
    const int j = idx & 7, l = (idx >> 3) & 63;
    const int ht = (idx >> 9) % 20, kt = idx / (512 * 20);
    const int q = l >> 4, n = l & 15;
    const int k = kt * 32 + q * 8 + j;
    float v = (ht < 16) ? W[k * 256 + ht * 16 + n]
                        : keys[((ht - 16) * 16 + n) * 256 + k];
    WBf[idx] = (_Float16)v;
}

// SW[tb][h] (f16) = stories[tb]@W  and  KS[tb][m] (f32) = stories[tb].keys[m]
__global__ __launch_bounds__(256, 4) void k_swks(const float* __restrict__ S,
                                                 const _Float16* __restrict__ WBf,
                                                 _Float16* __restrict__ SWo,
                                                 float* __restrict__ KSo) {
    const int tid = threadIdx.x, w = tid >> 6, l = tid & 63;
    const int col = l & 15, q = l >> 4;
    const size_t tb0 = ((size_t)blockIdx.x * 4 + w) * 16;

    f32x4 acc[20];
#pragma unroll
    for (int ht = 0; ht < 20; ++ht) acc[ht] = (f32x4)(0.f);

#pragma unroll
    for (int kt = 0; kt < 8; ++kt) {
        const float* ar = S + (tb0 + col) * 256 + kt * 32 + q * 8;
        f32x4 a0 = *(const f32x4*)ar;
        f32x4 a1 = *(const f32x4*)(ar + 4);
        FragA ah, al;
#pragma unroll
        for (int j = 0; j < 4; ++j) {
            _Float16 h0 = (_Float16)a0[j];
            ah.h[j] = h0; al.h[j] = (_Float16)(a0[j] - (float)h0);
            _Float16 h1 = (_Float16)a1[j];
            ah.h[4 + j] = h1; al.h[4 + j] = (_Float16)(a1[j] - (float)h1);
        }
        const _Float16* bp = WBf + ((size_t)kt * 20 * 64 + l) * 8;
#pragma unroll
        for (int ht = 0; ht < 20; ++ht) {
            FragA fb; fb.u = *(const u32x4*)(bp + ht * 512);
            acc[ht] = __builtin_amdgcn_mfma_f32_16x16x32_f16(ah.h, fb.h, acc[ht], 0, 0, 0);
            acc[ht] = __builtin_amdgcn_mfma_f32_16x16x32_f16(al.h, fb.h, acc[ht], 0, 0, 0);
        }
    }
#pragma unroll
    for (int ht = 0; ht < 20; ++ht)
#pragma unroll
        for (int r = 0; r < 4; ++r) {
            size_t tbr = tb0 + q * 4 + r;
            if (ht < 16) SWo[tbr * 256 + ht * 16 + col] = (_Float16)acc[ht][r];
            else         KSo[tbr * 64 + (ht - 16) * 16 + col] = acc[ht][r];
        }
}

// gates transpose: GT[bg=b*4+mt][t*16+row] -> out[t][mt*16+row][b]
__global__ __launch_bounds__(256) void k_gt(const float* __restrict__ GT,
                                            float* __restrict__ out) {
    __shared__ float tile[64][65];
    const int mt = blockIdx.x & 3;
    const int bT = (blockIdx.x >> 2) & 7;
    const int trT = blockIdx.x >> 5;
    const int tx = threadIdx.x & 63, ty = threadIdx.x >> 6;
    const int b0 = bT * 64, tr0 = trT * 64;
#pragma unroll 4
    for (int i = 0; i < 16; ++i) {
        int r = i * 4 + ty;
        tile[r][tx] = GT[((size_t)(b0 + r) * 4 + mt) * 2048 + tr0 + tx];
    }
    __syncthreads();
    const size_t gbase = (size_t)M * B * Hd;
#pragma unroll 4
    for (int i = 0; i < 16; ++i) {
        int r = i * 4 + ty;
        int tr = tr0 + r;
        out[gbase + (size_t)(tr >> 4) * (M * B) + (size_t)(mt * 16 + (tr & 15)) * B + b0 + tx]
            = tile[tx][r];
    }
}

// ---------------- main recurrent kernel ----------------
// R2 changes vs R1 (latency-bound at 2 waves/SIMD; per-SIMD MFMA only ~8% busy):
//  - stream double-buffer: t+1's stories/SW/KS/mask issued at top of step t,
//    consumed one full step later -> HBM latency off the critical chain.
//  - LDS-only barriers in the loop (s_waitcnt lgkmcnt(0) + s_barrier): no vmcnt
//    drain, so the prefetch stays in flight across both barriers.
//  - kc/pa moved to LDS (frees 32 VGPR to pay for the prefetch set; stays under
//    the 256-reg cap so occupancy is unchanged).
//  - split4 via v_cvt_pkrtz: packed split + packed ds_write_b64.
__global__ __launch_bounds__(256, 2)
void dynmem_main(const float* __restrict__ stories, const float* __restrict__ mask,
                 const float* __restrict__ keys, const float* __restrict__ prelu_a,
                 const _Float16* __restrict__ SW, const float* __restrict__ KS,
                 const float* __restrict__ KC, const _Float16* __restrict__ UBf,
                 float* __restrict__ GT, float* __restrict__ out) {
    __shared__ __align__(16) unsigned short Aph[16 * SP];
    __shared__ __align__(16) unsigned short Apl[16 * SP];
    __shared__ __align__(16) float part[4][16][4];   // [wave][m-row][gd,oc,cc,pad]
    __shared__ __align__(16) float kcs[16 * KP];     // kc tile, padded stride
    __shared__ __align__(16) float pas[256];         // prelu_a

    const int tid = threadIdx.x;
    const int w = tid >> 6, l = tid & 63;
    const int col = l & 15, q = l >> 4;     // col = this lane's m-row; q = h sub-block
    const int hq  = q * 4;                  // h offset within a 16-tile
    const int htb = w * 4;                  // this wave's 4 h-out tiles
    const int b  = blockIdx.x >> 2;
    const int mt = blockIdx.x & 3;
    const int m0 = mt * 16;
    const int bg = blockIdx.x;

    // ---- t-invariant: U^T A-fragments resident in VGPRs/AGPRs ----
    FragA bfr[8][4];
#pragma unroll
    for (int kt = 0; kt < 8; ++kt)
#pragma unroll
        for (int hti = 0; hti < 4; ++hti)
            bfr[kt][hti].u = *(const u32x4*)(UBf + ((size_t)(kt * 16 + htb + hti) * 64 + l) * 8);

    // kc, pa -> LDS
    for (int i = tid; i < 16 * 256; i += 256) {
        const int mm = i >> 8, h = i & 255;
        kcs[mm * KP + h] = KC[(size_t)(m0 + mm) * Hd + h];
    }
    pas[tid] = prelu_a[tid];

    f32x4 old_[4];
#pragma unroll
    for (int hti = 0; hti < 4; ++hti)
        old_[hti] = *(const f32x4*)(keys + (m0 + col) * Hd + (htb + hti) * 16 + hq);

    // okk = ||keys[m0+col]||^2 (for t=0 norm; afterwards ||old||==1)
    float okk = 0.f;
    {
        const float* kr = keys + (m0 + col) * Hd;
#pragma unroll 4
        for (int k = 0; k < 256; k += 4) {
            f32x4 kv = *(const f32x4*)(kr + k);
            okk = fmaf(kv[0], kv[0], okk); okk = fmaf(kv[1], kv[1], okk);
            okk = fmaf(kv[2], kv[2], okk); okk = fmaf(kv[3], kv[3], okk);
        }
    }
    // init A-planes = keys (unnormalized per reference)
#pragma unroll
    for (int hti = 0; hti < 4; ++hti) {
        u32x2 vh, vl;
        split4(old_[hti], vh, vl);
        *((u32x2*)(void*)(Aph + col * SP + (htb + hti) * 16 + hq)) = vh;
        *((u32x2*)(void*)(Apl + col * SP + (htb + hti) * 16 + hq)) = vl;
    }
    __syncthreads();

    // ---- stream double-buffer ----
    f32x4 sent_c[4]; half4 sw_c[4]; float ks_c, mv_c;
    {
        const size_t tb = (size_t)0 * B + b;
        mv_c = mask[b];
        ks_c = KS[tb * 64 + m0 + col];
#pragma unroll
        for (int hti = 0; hti < 4; ++hti) {
            const int h0 = (htb + hti) * 16 + hq;
            sent_c[hti] = *(const f32x4*)(stories + tb * Hd + h0);
            sw_c[hti]   = *(const half4*)(SW + tb * Hd + h0);
        }
    }

    for (int t = 0; t < T; ++t) {
        // ---- issue next step's streams (consumed next iteration) ----
        f32x4 sent_n[4]; half4 sw_n[4]; float ks_n, mv_n;
        {
            const int tn = (t + 1 < T) ? t + 1 : t;
            const size_t tb = (size_t)tn * B + b;
            mv_n = mask[tn * B + b];
            ks_n = KS[tb * 64 + m0 + col];
#pragma unroll
            for (int hti = 0; hti < 4; ++hti) {
                const int h0 = (htb + hti) * 16 + hq;
                sent_n[hti] = *(const f32x4*)(stories + tb * Hd + h0);
                sw_n[hti]   = *(const half4*)(SW + tb * Hd + h0);
            }
        }

        // ---- MFMA: acc[hti] = (U^T @ state^T) tile; A = bfr (regs), B = LDS planes ----
        f32x4 acc[4];
#pragma unroll
        for (int hti = 0; hti < 4; ++hti) acc[hti] = (f32x4)(0.f);

#pragma unroll
        for (int kt = 0; kt < 8; ++kt) {
            const half8 sh = *(const half8*)(const void*)(Aph + col * SP + kt * 32 + q * 8);
            const half8 sl = *(const half8*)(const void*)(Apl + col * SP + kt * 32 + q * 8);
#pragma unroll
            for (int hti = 0; hti < 4; ++hti)
                acc[hti] = __builtin_amdgcn_mfma_f32_16x16x32_f16(bfr[kt][hti].h, sh, acc[hti], 0, 0, 0);
#pragma unroll
            for (int hti = 0; hti < 4; ++hti)
                acc[hti] = __builtin_amdgcn_mfma_f32_16x16x32_f16(bfr[kt][hti].h, sl, acc[hti], 0, 0, 0);
        }

        // ---- candidate + per-lane partials over this lane's 16 h values ----
        float gd = 0.f, oc = 0.f, cc = 0.f;
#pragma unroll
        for (int hti = 0; hti < 4; ++hti) {
            const int h0 = (htb + hti) * 16 + hq;
            const f32x4 kcv = *(const f32x4*)(kcs + col * KP + h0);
            const f32x4 pav = *(const f32x4*)(pas + h0);
#pragma unroll
            for (int r = 0; r < 4; ++r) {
                float o = old_[hti][r];
                float x = acc[hti][r] + (float)sw_c[hti][r] + kcv[r];
                float c = (x < 0.f) ? pav[r] * x : x;    // PReLU
                acc[hti][r] = c;                          // keep candidate
                gd = fmaf(o, sent_c[hti][r], gd);
                oc = fmaf(o, c, oc);
                cc = fmaf(c, c, cc);
            }
        }
        // reduce across the 4 q-lanes sharing this m (= col): xor 16, 32
        gd += __shfl_xor(gd, 16); gd += __shfl_xor(gd, 32);
        oc += __shfl_xor(oc, 16); oc += __shfl_xor(oc, 32);
        cc += __shfl_xor(cc, 16); cc += __shfl_xor(cc, 32);
        if (q == 0) {
            f32x4 pv = {gd, oc, cc, 0.f};
            *(f32x4*)part[w][col] = pv;
        }
        bar_lds();   // barrier 1: partials ready; all A-plane reads complete

        // ---- phase B: every lane finalizes its own m (= col) ----
        f32x4 p0 = *(const f32x4*)part[0][col];
        f32x4 p1 = *(const f32x4*)part[1][col];
        f32x4 p2 = *(const f32x4*)part[2][col];
        f32x4 p3 = *(const f32x4*)part[3][col];
        float gdS = p0[0] + p1[0] + p2[0] + p3[0];
        float ocS = p0[1] + p1[1] + p2[1] + p3[1];
        float ccS = p0[2] + p1[2] + p2[2] + p3[2];
        float g   = 1.f / (1.f + __expf(-(gdS + ks_c)));
        float Gm  = g * mv_c;
        float ooc = (t == 0) ? okk : 1.0f;
        float nsq = fmaf(Gm, fmaf(Gm, ccS, 2.f * ocS), ooc);
        float scl = 1.f / fmaxf(sqrtf(nsq), 1e-12f);
        if (tid < 16) GT[(size_t)bg * 2048 + t * 16 + col] = g;

        // ---- state update + A-plane refresh ----
#pragma unroll
        for (int hti = 0; hti < 4; ++hti) {
            f32x4 nv;
#pragma unroll
            for (int r = 0; r < 4; ++r) {
                float n = fmaf(Gm, acc[hti][r], old_[hti][r]) * scl;
                old_[hti][r] = n;
                nv[r] = n;
            }
            u32x2 vh, vl;
            split4(nv, vh, vl);
            *((u32x2*)(void*)(Aph + col * SP + (htb + hti) * 16 + hq)) = vh;
            *((u32x2*)(void*)(Apl + col * SP + (htb + hti) * 16 + hq)) = vl;
        }
        bar_lds();   // barrier 2: A-planes ready for next step

        // ---- rotate stream buffers ----
#pragma unroll
        for (int i = 0; i < 4; ++i) { sent_c[i] = sent_n[i]; sw_c[i] = sw_n[i]; }
        ks_c = ks_n; mv_c = mv_n;
    }

    // ---- final memory out [M,B,H], exact f32 from registers ----
#pragma unroll
    for (int hti = 0; hti < 4; ++hti)
        *(f32x4*)(out + ((size_t)(m0 + col) * B + b) * Hd + (htb + hti) * 16 + hq) = old_[hti];
}

extern "C" void kernel_launch(void* const* d_in, const int* in_sizes, int n_in,
                              void* d_out, int out_size, void* d_ws, size_t ws_size,
                              hipStream_t stream) {
    const float* stories = (const float*)d_in[0];
    const float* mask    = (const float*)d_in[1];
    const float* keys    = (const float*)d_in[2];
    const float* U       = (const float*)d_in[3];
    const float* W       = (const float*)d_in[4];
    const float* V       = (const float*)d_in[5];
    const float* prelu_a = (const float*)d_in[6];
    float* out = (float*)d_out;

    // workspace carve-up (~67.5 MB)
    _Float16* SW  = (_Float16*)d_ws;                   // 16,777,216 f16 (33.55 MB)
    float*    KS  = (float*)(SW + 16777216);           //  4,194,304 f32 (16.78 MB)
    float*    KC  = KS + 4194304;                      //     16,384 f32
    _Float16* UBf = (_Float16*)(KC + 16384);           //     65,536 f16
    _Float16* WBf = UBf + 65536;                       //     81,920 f16
    float*    GT  = (float*)(WBf + 81920);             //  4,194,304 f32 (16.78 MB)

    k_kc   <<<dim3(64),   dim3(256), 0, stream>>>(keys, V, KC);
    k_fragU<<<dim3(256),  dim3(256), 0, stream>>>(U, UBf);
    k_fragW<<<dim3(320),  dim3(256), 0, stream>>>(W, keys, WBf);
    k_swks <<<dim3(1024), dim3(256), 0, stream>>>(stories, WBf, SW, KS);
    dynmem_main<<<dim3(2048), dim3(256), 0, stream>>>(stories, mask, keys, prelu_a,
                                                      SW, KS, KC, UBf, GT, out);
    k_gt   <<<dim3(1024), dim3(256), 0, stream>>>(GT, out);
}